// Round 10
// baseline (924.997 us; speedup 1.0000x reference)
//
#include <hip/hip_runtime.h>

#define TSEQ 2048
#define BATCH 16
#define EMBD 256
#define HID 512
#define NG 1536            // 3*HID
#define NVOCAB 256
#define MROWS (TSEQ*BATCH) // 32768
#define CM 8192            // chunk rows (4 chunks)

typedef __attribute__((ext_vector_type(8))) unsigned short u16x8;
typedef __attribute__((ext_vector_type(8))) short s16x8;
typedef __attribute__((ext_vector_type(4))) float f32x4;

__device__ __forceinline__ float bf2f(unsigned short u) {
  union { unsigned u; float f; } x; x.u = ((unsigned)u) << 16; return x.f;
}
__device__ __forceinline__ unsigned short f2bf(float v) {
  union { float f; unsigned u; } x; x.f = v;
  unsigned r = (x.u + 0x7fffu + ((x.u >> 16) & 1u)) >> 16;
  return (unsigned short)r;
}
__device__ __forceinline__ float fast_rcp(float x) { return __builtin_amdgcn_rcpf(x); }
__device__ __forceinline__ float fast_sigmoid(float x) {
  float e = __builtin_amdgcn_exp2f(fminf(-1.442695041f * x, 80.f));
  return fast_rcp(1.f + e);
}
__device__ __forceinline__ float fast_tanh(float x) {
  float e = __builtin_amdgcn_exp2f(fminf(-2.885390082f * x, 80.f));
  return (1.f - e) * fast_rcp(1.f + e);
}
__device__ __forceinline__ void lds_cp16(const void* g, void* l) {
  __builtin_amdgcn_global_load_lds((const __attribute__((address_space(1))) void*)g,
                                   (__attribute__((address_space(3))) void*)l, 16, 0, 0);
}

// ---- embed: H0[m][e] bf16, m = t*16+b ----
__global__ __launch_bounds__(256) void embed_k(const int* __restrict__ x,
                                               const float* __restrict__ emb,
                                               unsigned short* __restrict__ H0) {
  int idx = blockIdx.x * 256 + threadIdx.x;   // 1M threads
  int m = idx >> 5, e8 = (idx & 31) * 8;
  int tok = x[(m & 15) * TSEQ + (m >> 4)];
  const float* e = emb + (size_t)tok * EMBD + e8;
  float4 v0 = *(const float4*)e;
  float4 v1 = *(const float4*)(e + 4);
  u16x8 o;
  o[0]=f2bf(v0.x); o[1]=f2bf(v0.y); o[2]=f2bf(v0.z); o[3]=f2bf(v0.w);
  o[4]=f2bf(v1.x); o[5]=f2bf(v1.y); o[6]=f2bf(v1.z); o[7]=f2bf(v1.w);
  *(u16x8*)(H0 + (size_t)m * EMBD + e8) = o;
}

// ---- weight transpose+convert: Wt[n][k] bf16 = W[k][n] f32 ----
__global__ __launch_bounds__(256) void wt_k(const float* __restrict__ W,
                                            unsigned short* __restrict__ Wt,
                                            int K, int N) {
  __shared__ float tile[32][33];
  int n0 = blockIdx.x * 32, k0 = blockIdx.y * 32;
  int tx = threadIdx.x, ty = threadIdx.y;
#pragma unroll
  for (int i = 0; i < 4; ++i)
    tile[ty + i * 8][tx] = W[(size_t)(k0 + ty + i * 8) * N + n0 + tx];
  __syncthreads();
#pragma unroll
  for (int i = 0; i < 4; ++i)
    Wt[(size_t)(n0 + ty + i * 8) * K + k0 + tx] = f2bf(tile[tx][ty + i * 8]);
}

// ---- MFMA GEMM: D[m][n] = A[m][k] @ Wt[n][k]^T  (both bf16, k-contiguous) ----
// BM=256, BN=128, BK=32, 256 thr = 4 waves (2x2 of 128x64 wave-tiles), 128 MFMA/K-step.
// LDS-read bytes/MFMA: 375 (was 500 at 64x64 wave-tiles) — the round-10 lever.
// BK stays 32 (BK=64 regressed +72 us in round 7 — do not re-try).
// EPI=0: gates -> act -> Y[m][1536] bf16 (2-pass LDS re-tile, coalesced)
// EPI=1: decoder -> f32 permuted store to out (B,T,V)
template <int K, int EPI>
__global__ __launch_bounds__(256, 2) void gemm_k(const unsigned short* __restrict__ A,
                                                 const unsigned short* __restrict__ Bt,
                                                 const float* __restrict__ bias,
                                                 unsigned short* __restrict__ Yg,
                                                 float* __restrict__ Out) {
  __shared__ unsigned short smem[16384];  // 32 KB: staging A[0,8192) B[8192,12288); epilogue all
  unsigned short* sA = smem;              // 256 rows x 32 k (64 B rows)
  unsigned short* sB = smem + 8192;       // 128 rows x 32 k
  const int tid = threadIdx.x;
  const int m0 = blockIdx.y * 256;
  const int n0 = blockIdx.x * 128;
  const int lane = tid & 63, wave = tid >> 6;
  const int wm = (wave >> 1) * 128, wn = (wave & 1) * 64;
  const int l15 = lane & 15, lg = lane >> 4;

  f32x4 acc[8][4] = {};

  for (int k0 = 0; k0 < K; k0 += 32) {
    // stage A (256x32): 4 chunks/thread; B (128x32): 2 chunks/thread. Source pre-unswizzled.
#pragma unroll
    for (int j = 0; j < 4; ++j) {
      int fl = j * 256 + tid;                       // 1024 16-B chunks
      int m = fl >> 2;
      int cl = ((fl & 3) << 4) ^ (((m >> 1) & 3) << 4);   // logical byte-col
      lds_cp16(A + (size_t)(m0 + m) * K + k0 + (cl >> 1), &sA[fl * 8]);
    }
#pragma unroll
    for (int j = 0; j < 2; ++j) {
      int fl = j * 256 + tid;                       // 512 16-B chunks
      int m = fl >> 2;
      int cl = ((fl & 3) << 4) ^ (((m >> 1) & 3) << 4);
      lds_cp16(Bt + (size_t)(n0 + m) * K + k0 + (cl >> 1), &sB[fl * 8]);
    }
    __syncthreads();   // drains vmcnt(0) before barrier

    s16x8 af[8], bf[4];
#pragma unroll
    for (int i = 0; i < 8; ++i) {
      int ma = wm + i * 16 + l15;
      int ca = (lg * 16) ^ (((ma >> 1) & 3) << 4);
      af[i] = *(const s16x8*)&sA[ma * 32 + (ca >> 1)];
    }
#pragma unroll
    for (int j = 0; j < 4; ++j) {
      int nb = wn + j * 16 + l15;
      int cb = (lg * 16) ^ (((nb >> 1) & 3) << 4);
      bf[j] = *(const s16x8*)&sB[nb * 32 + (cb >> 1)];
    }
#pragma unroll
    for (int i = 0; i < 8; ++i)
#pragma unroll
      for (int j = 0; j < 4; ++j)
        acc[i][j] = __builtin_amdgcn_mfma_f32_16x16x32_bf16(af[i], bf[j], acc[i][j], 0, 0, 0);
    __syncthreads();
  }

  if (EPI == 0) {
    // epilogue: bias + activation, 2-pass LDS re-tile (128 rows/pass), coalesced Y store
    const int acttype = n0 >> 9;  // 0: z->tanh, 1/2: f,o->sigmoid
    const int wr = wave >> 1;
#pragma unroll
    for (int p = 0; p < 2; ++p) {
      if (wr == p) {
#pragma unroll
        for (int i = 0; i < 8; ++i)
#pragma unroll
          for (int j = 0; j < 4; ++j)
#pragma unroll
            for (int r = 0; r < 4; ++r) {
              int mm = i * 16 + lg * 4 + r;        // 0..127 within pass
              int nn = wn + j * 16 + l15;          // 0..127
              float v = acc[i][j][r] + bias[n0 + nn];
              v = (acttype == 0) ? fast_tanh(v) : fast_sigmoid(v);
              smem[mm * 128 + (nn ^ ((mm & 7) << 3))] = f2bf(v);
            }
      }
      __syncthreads();
#pragma unroll
      for (int it = 0; it < 8; ++it) {
        int fl = it * 256 + tid;                   // 2048 16-B chunks
        int mm = fl >> 4, ng = (fl & 15) * 8;
        u16x8 v = *(const u16x8*)&smem[mm * 128 + (ng ^ ((mm & 7) << 3))];
        *(u16x8*)(Yg + (size_t)(m0 + p * 128 + mm) * NG + n0 + ng) = v;
      }
      __syncthreads();
    }
  } else {
    // decoder epilogue: f32 permuted store out[b][t][v]
#pragma unroll
    for (int i = 0; i < 8; ++i)
#pragma unroll
      for (int j = 0; j < 4; ++j)
#pragma unroll
        for (int r = 0; r < 4; ++r) {
          int mmg = m0 + wm + i * 16 + lg * 4 + r;
          int nn = n0 + wn + j * 16 + l15;
          float v = acc[i][j][r] + bias[nn];
          int b = mmg & 15, t = mmg >> 4;
          Out[((size_t)b * TSEQ + t) * NVOCAB + nn] = v;
        }
  }
}

// ---- segment-parallel fo-pool scan, fused 3-phase, one kernel per chunk ----
// (round-9 version: 8 segs x 32 h, 64-B coalesced reads; proven 701 us config)
template <int LGS>
__global__ __launch_bounds__(256) void scan2_k(const unsigned short* __restrict__ Y,
                                               unsigned short* __restrict__ Hout,
                                               float* __restrict__ cst,
                                               int m0, int init) {
  const int S = 1 << LGS;            // dilation slots
  const int SEGLEN = 1024 >> LGS;    // CM/(S*8)
  __shared__ float As[256], Bs[256], Ci[256];   // [8 seg][32 h]

  const int tid = threadIdx.x;
  const int hi = tid & 31, seg = tid >> 5;
  const int s = blockIdx.x >> 4, hg = blockIdx.x & 15;   // grid = S*16 blocks
  const int h = hg * 32 + hi;
  const int mb = seg * SEGLEN * S + s;
  const size_t step = (size_t)S * NG;

  // phase A: per-segment affine (a = prod f, b = local scan from 0)
  float a = 1.f, c = 0.f;
  {
    const unsigned short* p = Y + (size_t)mb * NG + h;
#pragma unroll 8
    for (int t = 0; t < SEGLEN; ++t) {
      float z = bf2f(p[0]);
      float f = bf2f(p[512]);
      a *= f;
      c = __builtin_fmaf(f, c - z, z);
      p += step;
    }
  }
  As[tid] = a;
  Bs[tid] = c;
  __syncthreads();

  // phase B: serial combine over 8 segments (32 lanes active), carry from/to cst
  if (seg == 0) {
    float cc = init ? 0.f : cst[s * 512 + h];
#pragma unroll
    for (int k = 0; k < 8; ++k) {
      Ci[k * 32 + hi] = cc;
      cc = __builtin_fmaf(As[k * 32 + hi], cc, Bs[k * 32 + hi]);
    }
    cst[s * 512 + h] = cc;
  }
  __syncthreads();

  // phase C: rescan with correct carry-in, write H (coalesced 64-B chunks in h)
  c = Ci[tid];
  const unsigned short* p = Y + (size_t)mb * NG + h;
  unsigned short* hb = Hout + (size_t)(m0 + mb) * HID + h;
  const size_t stepH = (size_t)S * HID;
#pragma unroll 4
  for (int t = 0; t < SEGLEN; ++t) {
    float z = bf2f(p[0]);
    float f = bf2f(p[512]);
    float o = bf2f(p[1024]);
    c = __builtin_fmaf(f, c - z, z);
    *hb = f2bf(o * c);
    p += step;
    hb += stepH;
  }
}

extern "C" void kernel_launch(void* const* d_in, const int* in_sizes, int n_in,
                              void* d_out, int out_size, void* d_ws, size_t ws_size,
                              hipStream_t stream) {
  const int* x = (const int*)d_in[0];
  const float* emb = (const float*)d_in[1];
  const float* Wl[4] = {(const float*)d_in[2], (const float*)d_in[4],
                        (const float*)d_in[6], (const float*)d_in[8]};
  const float* bl[4] = {(const float*)d_in[3], (const float*)d_in[5],
                        (const float*)d_in[7], (const float*)d_in[9]};
  const float* decW = (const float*)d_in[10];
  const float* decb = (const float*)d_in[11];
  float* out = (float*)d_out;

  // ws layout: identical to proven-safe round-4/5/9 layout (64,749,568 B).
  if (ws_size < 64749568ull) return;
  char* ws = (char*)d_ws;
  unsigned short* Y   = (unsigned short*)(ws);                        // 8192*1536*2 = 24 MB
  unsigned short* Ha  = (unsigned short*)(ws + 25165824ull);          // 32768*512*2 = 32 MB
  unsigned short* Wt0 = (unsigned short*)(ws + 58720256ull);          // 1536*256*2
  unsigned short* Wt1 = (unsigned short*)(ws + 59506688ull);          // 1536*512*2
  unsigned short* Wt2 = (unsigned short*)(ws + 61079552ull);
  unsigned short* Wt3 = (unsigned short*)(ws + 62652416ull);
  unsigned short* WtD = (unsigned short*)(ws + 64225280ull);          // 256*512*2
  float*          cst = (float*)(ws + 64487424ull);                   // 65536*4 = 256 KB
  unsigned short* Hb  = (unsigned short*)d_out;                       // scratch until decoder

  // weights: transpose+convert to bf16 [n][k]
  wt_k<<<dim3(NG / 32, EMBD / 32), dim3(32, 8), 0, stream>>>(Wl[0], Wt0, EMBD, NG);
  wt_k<<<dim3(NG / 32, HID / 32), dim3(32, 8), 0, stream>>>(Wl[1], Wt1, HID, NG);
  wt_k<<<dim3(NG / 32, HID / 32), dim3(32, 8), 0, stream>>>(Wl[2], Wt2, HID, NG);
  wt_k<<<dim3(NG / 32, HID / 32), dim3(32, 8), 0, stream>>>(Wl[3], Wt3, HID, NG);
  wt_k<<<dim3(NVOCAB / 32, HID / 32), dim3(32, 8), 0, stream>>>(decW, WtD, HID, NVOCAB);

  // embedding -> Ha [32768][256] bf16
  embed_k<<<(MROWS * (EMBD / 8)) / 256, 256, 0, stream>>>(x, emb, Ha);

  unsigned short* Wts[4] = {Wt0, Wt1, Wt2, Wt3};
  unsigned short* Hbuf[2] = {Ha, Hb};
  for (int L = 0; L < 4; ++L) {
    unsigned short* Hin = Hbuf[L & 1];
    unsigned short* Hout = Hbuf[(L + 1) & 1];
    const int Kd = (L == 0) ? EMBD : HID;
    for (int ch = 0; ch < MROWS / CM; ++ch) {
      const unsigned short* Ach = Hin + (size_t)ch * CM * Kd;
      if (L == 0)
        gemm_k<EMBD, 0><<<dim3(NG / 128, CM / 256), 256, 0, stream>>>(Ach, Wts[L], bl[L], Y, nullptr);
      else
        gemm_k<HID, 0><<<dim3(NG / 128, CM / 256), 256, 0, stream>>>(Ach, Wts[L], bl[L], Y, nullptr);
      switch (L) {
        case 0: scan2_k<4><<<16 * 16, 256, 0, stream>>>(Y, Hout, cst, ch * CM, ch == 0); break;
        case 1: scan2_k<5><<<32 * 16, 256, 0, stream>>>(Y, Hout, cst, ch * CM, ch == 0); break;
        case 2: scan2_k<6><<<64 * 16, 256, 0, stream>>>(Y, Hout, cst, ch * CM, ch == 0); break;
        case 3: scan2_k<7><<<128 * 16, 256, 0, stream>>>(Y, Hout, cst, ch * CM, ch == 0); break;
      }
    }
  }

  // decoder: out[b][t][v] = Ha @ decW + decb
  gemm_k<HID, 1><<<dim3(NVOCAB / 128, MROWS / 256), 256, 0, stream>>>(Hbuf[0], WtD, decb, nullptr, out);
}